// Round 3
// baseline (521.169 us; speedup 1.0000x reference)
//
#include <hip/hip_runtime.h>
#include <cstdint>
#include <cstddef>

typedef float f32x4 __attribute__((ext_vector_type(4)));
typedef short bf16x8 __attribute__((ext_vector_type(8)));

#define DEVI __device__ __forceinline__

namespace {

constexpr int BB = 8, LL = 1024, CC = 1536;
constexpr int HH = 8, KDIM = 64, VDIM = 192;
constexpr int NFEAT = 192, FSZ = 32;
constexpr float SCL = 0.125f;
constexpr int MR = BB * LL;     // 8192
constexpr int NQK = HH * KDIM;  // 512
constexpr int NVD = HH * VDIM;  // 1536

DEVI short f2bf(float f) {
  unsigned u = __float_as_uint(f);
  u = (u + 0x7FFFu + ((u >> 16) & 1u)) >> 16;
  return (short)u;
}

DEVI void gload_lds16(const void* g, void* l) {
  __builtin_amdgcn_global_load_lds(
      (const __attribute__((address_space(1))) void*)g,
      (__attribute__((address_space(3))) void*)l, 16, 0, 0);
}

// ---------------- convert f32 -> bf16 ----------------
__global__ void k_f32_to_bf16(const float* __restrict__ src, short* __restrict__ dst, int n) {
  int i0 = (blockIdx.x * blockDim.x + threadIdx.x) * 4;
  int stride = gridDim.x * blockDim.x * 4;
  for (int i = i0; i < n; i += stride) {
    float4 v = *reinterpret_cast<const float4*>(src + i);
    short4 o = { f2bf(v.x), f2bf(v.y), f2bf(v.z), f2bf(v.w) };
    *reinterpret_cast<short4*>(dst + i) = o;
  }
}

// ---------------- transpose f32 [R][Cd] -> bf16 [Cd][R] ----------------
__global__ void k_transpose_w(const float* __restrict__ src, short* __restrict__ dst, int R, int Cd) {
  __shared__ float tile[32][33];
  int c0 = blockIdx.x * 32, r0 = blockIdx.y * 32;
  int tx = threadIdx.x, ty = threadIdx.y;   // (32, 8)
  #pragma unroll
  for (int i = 0; i < 4; i++)
    tile[ty + i * 8][tx] = src[(size_t)(r0 + ty + i * 8) * Cd + c0 + tx];
  __syncthreads();
  #pragma unroll
  for (int i = 0; i < 4; i++)
    dst[(size_t)(c0 + ty + i * 8) * R + r0 + tx] = f2bf(tile[tx][ty + i * 8]);
}

// ---------------- V: [8192][1536] bf16 -> Vt [64][192][1024] bf16 ----------------
__global__ void k_transpose_v(const short* __restrict__ vb, short* __restrict__ vt) {
  __shared__ short tile[32][33];
  int bh = blockIdx.z;
  int b = bh >> 3, h = bh & 7;
  int v0 = blockIdx.y * 32;
  int s0 = blockIdx.x * 32;
  int tx = threadIdx.x, ty = threadIdx.y;
  #pragma unroll
  for (int i = 0; i < 4; i++)
    tile[ty + i * 8][tx] = vb[(size_t)(b * LL + s0 + ty + i * 8) * NVD + h * VDIM + v0 + tx];
  __syncthreads();
  #pragma unroll
  for (int i = 0; i < 4; i++)
    vt[(size_t)bh * VDIM * LL + (size_t)(v0 + ty + i * 8) * LL + s0 + tx] = tile[tx][ty + i * 8];
}

// ---------------- gamma pdf global max ----------------
__global__ void k_pdfmax(unsigned* slot) {
  int tid = blockIdx.x * blockDim.x + threadIdx.x;
  int nth = gridDim.x * blockDim.x;
  double lmax = 0.0;
  for (int idx = tid; idx < 2047 * FSZ; idx += nth) {
    int j = idx >> 5, i = idx & 31;
    double ap = (double)(j >= 1023 ? j - 1023 : 1023 - j);
    double mean = 32.0 + 32.0 * (double)i;
    double conc = (mean * (1.0 / 16.0)) * (mean * (1.0 / 16.0));
    double rate = mean * (1.0 / 256.0);
    double lp = (conc - 1.0) * log(ap) - rate * ap - lgamma(conc) + conc * log(rate);
    double pdf = exp(lp) + 1e-8;
    lmax = fmax(lmax, pdf);
  }
  float fv = (float)lmax;
  #pragma unroll
  for (int o = 32; o > 0; o >>= 1) fv = fmaxf(fv, __shfl_down(fv, o, 64));
  if ((threadIdx.x & 63) == 0) atomicMax(slot, __float_as_uint(fv));
}

// ---------------- build RB: row 0 = zeros, row j+1 = (basis[j] @ WR) ----------------
__global__ void k_build_r(const float* __restrict__ WR, const unsigned* __restrict__ slot,
                          short* __restrict__ rbuf) {
  __shared__ float feats[NFEAT];
  int jp = blockIdx.x;       // 0..2047
  int tid = threadIdx.x;     // 256
  if (jp == 0) {
    if (tid < KDIM) rbuf[tid] = 0;
    return;
  }
  int j = jp - 1;            // 0..2046
  int pos = j - (LL - 1);
  int api = pos < 0 ? -pos : pos;
  double ap = (double)api;
  float sgn = pos > 0 ? 1.0f : (pos < 0 ? -1.0f : 0.0f);
  if (tid < FSZ) {
    double xhl = 3.0 + 7.0 * (double)tid / 31.0;
    double hl = exp2(xhl);
    float fe = (float)exp2(-ap / hl);
    feats[tid] = fe; feats[FSZ + tid] = sgn * fe;
  } else if (tid < 2 * FSZ) {
    int i = tid - FSZ;
    double cw = exp2((double)(i + 1)) - 1.0;
    float fc = cw > ap ? 1.0f : 0.0f;
    feats[2 * FSZ + i] = fc; feats[3 * FSZ + i] = sgn * fc;
  } else if (tid < 3 * FSZ) {
    int i = tid - 2 * FSZ;
    double mean = 32.0 + 32.0 * (double)i;
    double conc = (mean * (1.0 / 16.0)) * (mean * (1.0 / 16.0));
    double rate = mean * (1.0 / 256.0);
    double lp = (conc - 1.0) * log(ap) - rate * ap - lgamma(conc) + conc * log(rate);
    double pdf = exp(lp) + 1e-8;
    float fg = (float)(pdf / (double)__uint_as_float(*slot));
    feats[4 * FSZ + i] = fg; feats[5 * FSZ + i] = sgn * fg;
  }
  __syncthreads();
  if (tid < KDIM) {
    float acc = 0.f;
    #pragma unroll 4
    for (int f = 0; f < NFEAT; f++) acc += feats[f] * WR[f * KDIM + tid];
    rbuf[jp * KDIM + tid] = f2bf(acc);
  }
}

// ---------------- bf16 MFMA GEMM: C = A[M,K] @ Bt[N,K]^T + bias ----------------
// MODE 0: bf16 store to D0.  MODE 1: D0=(val)*SCL bf16, D1=(val+bias2)*SCL bf16.  MODE 2: f32 store.
template<int MODE>
__global__ __launch_bounds__(256, 2)
void k_gemm(const short* __restrict__ A, const short* __restrict__ Bt,
            int Mdim, int Ndim, int Kdim,
            const float* __restrict__ bias, const float* __restrict__ bias2,
            void* __restrict__ D0, void* __restrict__ D1) {
  __shared__ short As[128][64];
  __shared__ short Bs[128][64];
  int m0 = blockIdx.x * 128, n0 = blockIdx.y * 128;
  int tid = threadIdx.x;
  int w = tid >> 6, l = tid & 63;
  int wr = (w >> 1) * 64, wc = (w & 1) * 64;

  f32x4 acc[4][4] = {};

  const short* ga = A + (size_t)(m0 + w * 8 + (l >> 3)) * Kdim + (l & 7) * 8;
  const short* gb = Bt + (size_t)(n0 + w * 8 + (l >> 3)) * Kdim + (l & 7) * 8;

  for (int k0 = 0; k0 < Kdim; k0 += 64) {
    #pragma unroll
    for (int i = 0; i < 4; i++) {
      gload_lds16(ga + (size_t)(i * 32) * Kdim + k0, &As[i * 32 + w * 8][0]);
      gload_lds16(gb + (size_t)(i * 32) * Kdim + k0, &Bs[i * 32 + w * 8][0]);
    }
    __syncthreads();
    #pragma unroll
    for (int kk = 0; kk < 2; kk++) {
      bf16x8 af[4], bfr[4];
      #pragma unroll
      for (int mi = 0; mi < 4; mi++)
        af[mi] = *(const bf16x8*)&As[wr + mi * 16 + (l & 15)][kk * 32 + (l >> 4) * 8];
      #pragma unroll
      for (int ni = 0; ni < 4; ni++)
        bfr[ni] = *(const bf16x8*)&Bs[wc + ni * 16 + (l & 15)][kk * 32 + (l >> 4) * 8];
      #pragma unroll
      for (int mi = 0; mi < 4; mi++)
        #pragma unroll
        for (int ni = 0; ni < 4; ni++)
          acc[mi][ni] = __builtin_amdgcn_mfma_f32_16x16x32_bf16(af[mi], bfr[ni], acc[mi][ni], 0, 0, 0);
    }
    __syncthreads();
  }

  int lr = (l >> 4) * 4, lc = l & 15;
  #pragma unroll
  for (int ni = 0; ni < 4; ni++) {
    int col = n0 + wc + ni * 16 + lc;
    float bvv = bias[col];
    float bv2 = (MODE == 1) ? bias2[col] : 0.f;
    #pragma unroll
    for (int mi = 0; mi < 4; mi++) {
      #pragma unroll
      for (int r = 0; r < 4; r++) {
        int row = m0 + wr + mi * 16 + lr + r;
        float val = acc[mi][ni][r] + bvv;
        if (MODE == 0) {
          ((short*)D0)[(size_t)row * Ndim + col] = f2bf(val);
        } else if (MODE == 1) {
          ((short*)D0)[(size_t)row * Ndim + col] = f2bf(val * SCL);
          ((short*)D1)[(size_t)row * Ndim + col] = f2bf((val + bv2) * SCL);
        } else {
          ((float*)D0)[(size_t)row * Ndim + col] = val;
        }
      }
    }
  }
}

// ---------------- barrier-free flash attention ----------------
// Wave-parity q-ownership: w0 owns even local rows {0,2,..30}, w1 {32..62},
// w2 odd {1..31}, w3 {33..63}. Scores computed transposed:
//   s[kt] = mfma(K_rows, Q^T) + mfma(RB_rows, Qs^T)
// so lane lc holds q-column qloc(lc) and 16 k-values -> in-register softmax
// (15 ops + 2 shfl_xor). P goes through a wave-PRIVATE LDS slice only
// (layout change for the PV A-fragment); K/RB/V fragments are read directly
// from global (L2-resident, verified by R2 FETCH_SIZE). Zero __syncthreads.
__global__ __launch_bounds__(256, 4)
void k_attn(const short* __restrict__ Qp, const short* __restrict__ Qs,
            const short* __restrict__ Kb, const short* __restrict__ Vt,
            const short* __restrict__ Rb, short* __restrict__ AO) {
  __shared__ short sP[64][72];   // wave w: rows [w*16, w*16+16), private

  int bid = blockIdx.x;
  int swz = (bid & 7) * 128 + (bid >> 3);   // XCD-contiguous bh
  int qt = swz & 15, bh = swz >> 4;
  int b = bh >> 3, h = bh & 7;
  int q0 = qt * 64;
  int tid = threadIdx.x;
  int w = tid >> 6, l = tid & 63;
  int hi = l >> 4, lc = l & 15;

  bool evenw = (w & 2) == 0;
  int base = (w & 1) * 32;
  int par = evenw ? 0 : 1;

  // Q fragments (B operands): lane lc holds its q-row's vector, slice hi.
  int qglob = q0 + base + par + 2 * lc;
  const short* qpg = Qp + (size_t)(b * LL + qglob) * NQK + h * KDIM + hi * 8;
  bf16x8 bq1[2] = { *(const bf16x8*)&qpg[0], *(const bf16x8*)&qpg[32] };
  int qsrow = (q0 + base) / 2 + par + lc;
  const short* qsg = Qs + (size_t)(b * LL + qsrow) * NQK + h * KDIM + hi * 8;
  bf16x8 bq2[2] = { *(const bf16x8*)&qsg[0], *(const bf16x8*)&qsg[32] };

  const short* kg = Kb + (size_t)(b * LL) * NQK + h * KDIM;
  const short* vg = Vt + (size_t)bh * VDIM * LL;
  const short* rg = Rb + (size_t)(evenw ? 1024 : 0) * KDIM;

  float mrun = -INFINITY, lrun = 0.f;   // for q=qglob (replicated across hi)
  f32x4 oacc[12] = {};

  for (int k0 = 0; k0 < LL; k0 += 64) {
    // scores (transposed): s[kt][r] = S[k=k0+kt*16+4*hi+r][q=qglob]
    f32x4 s[4] = {};
    #pragma unroll
    for (int kt = 0; kt < 4; kt++) {
      const short* ka = &kg[(size_t)(k0 + kt * 16 + lc) * NQK];
      const short* ra = &rg[(size_t)(k0 + kt * 16 + lc) * KDIM];
      #pragma unroll
      for (int kk = 0; kk < 2; kk++) {
        bf16x8 af = *(const bf16x8*)&ka[kk * 32 + hi * 8];
        s[kt] = __builtin_amdgcn_mfma_f32_16x16x32_bf16(af, bq1[kk], s[kt], 0, 0, 0);
        bf16x8 ar = *(const bf16x8*)&ra[kk * 32 + hi * 8];
        s[kt] = __builtin_amdgcn_mfma_f32_16x16x32_bf16(ar, bq2[kk], s[kt], 0, 0, 0);
      }
    }

    // in-register online softmax over the 64 k's of this tile
    float mx = -INFINITY;
    #pragma unroll
    for (int kt = 0; kt < 4; kt++)
      #pragma unroll
      for (int r = 0; r < 4; r++) mx = fmaxf(mx, s[kt][r]);
    mx = fmaxf(mx, __shfl_xor(mx, 16, 64));
    mx = fmaxf(mx, __shfl_xor(mx, 32, 64));
    float mnew = fmaxf(mrun, mx);
    float fac = __expf(mrun - mnew);
    mrun = mnew;
    float ps = 0.f;
    short4 pk[4];
    #pragma unroll
    for (int kt = 0; kt < 4; kt++) {
      float p0 = __expf(s[kt][0] - mnew);
      float p1 = __expf(s[kt][1] - mnew);
      float p2 = __expf(s[kt][2] - mnew);
      float p3 = __expf(s[kt][3] - mnew);
      ps += (p0 + p1) + (p2 + p3);
      pk[kt].x = f2bf(p0); pk[kt].y = f2bf(p1);
      pk[kt].z = f2bf(p2); pk[kt].w = f2bf(p3);
    }
    ps += __shfl_xor(ps, 16, 64);
    ps += __shfl_xor(ps, 32, 64);
    lrun = lrun * fac + ps;

    // write P (wave-private slice): lane (hi,lc) -> row lc, cols kt*16+4*hi..+3
    #pragma unroll
    for (int kt = 0; kt < 4; kt++)
      *(short4*)&sP[w * 16 + lc][kt * 16 + 4 * hi] = pk[kt];

    // rescale O by fac of acc-row i=4*hi+r (fac lives in lane i)
    float fq[4];
    #pragma unroll
    for (int r = 0; r < 4; r++) fq[r] = __shfl(fac, 4 * hi + r, 64);
    #pragma unroll
    for (int ni = 0; ni < 12; ni++)
      #pragma unroll
      for (int r = 0; r < 4; r++) oacc[ni][r] *= fq[r];

    // PV: A = P rows (this wave's 16 q's), B = V cols (all 192)
    bf16x8 pa0 = *(const bf16x8*)&sP[w * 16 + lc][hi * 8];
    bf16x8 pa1 = *(const bf16x8*)&sP[w * 16 + lc][32 + hi * 8];
    #pragma unroll
    for (int ni = 0; ni < 12; ni++) {
      const short* vb = &vg[(size_t)(ni * 16 + lc) * LL + k0 + hi * 8];
      bf16x8 bv0 = *(const bf16x8*)&vb[0];
      bf16x8 bv1 = *(const bf16x8*)&vb[32];
      oacc[ni] = __builtin_amdgcn_mfma_f32_16x16x32_bf16(pa0, bv0, oacc[ni], 0, 0, 0);
      oacc[ni] = __builtin_amdgcn_mfma_f32_16x16x32_bf16(pa1, bv1, oacc[ni], 0, 0, 0);
    }
  }

  // epilogue: normalize by 1/l (broadcast from softmax-owner lane) and store
  float iv = 1.0f / lrun;
  float ivr[4];
  #pragma unroll
  for (int r = 0; r < 4; r++) ivr[r] = __shfl(iv, 4 * hi + r, 64);
  #pragma unroll
  for (int r = 0; r < 4; r++) {
    int qrow = q0 + base + par + 2 * (4 * hi + r);
    short* ao = AO + (size_t)(b * LL + qrow) * NVD + h * VDIM;
    #pragma unroll
    for (int ni = 0; ni < 12; ni++)
      ao[ni * 16 + lc] = f2bf(oacc[ni][r] * ivr[r]);
  }
}

}  // namespace

extern "C" void kernel_launch(void* const* d_in, const int* in_sizes, int n_in,
                              void* d_out, int out_size, void* d_ws, size_t ws_size,
                              hipStream_t stream) {
  (void)in_sizes; (void)n_in; (void)out_size; (void)ws_size;
  const float* x  = (const float*)d_in[0];
  const float* Wq = (const float*)d_in[1];
  const float* bq = (const float*)d_in[2];
  const float* Wk = (const float*)d_in[3];
  const float* bk = (const float*)d_in[4];
  const float* Wv = (const float*)d_in[5];
  const float* bv = (const float*)d_in[6];
  const float* Wo = (const float*)d_in[7];
  const float* bo = (const float*)d_in[8];
  const float* WR = (const float*)d_in[9];
  const float* uu = (const float*)d_in[10];
  // d_in[11] (v) intentionally unused: term4 is constant along the softmax axis.

  char* ws = (char*)d_ws;
  size_t off = 0;
  auto alloc = [&](size_t bytes) -> void* {
    void* p = ws + off;
    off += (bytes + 255) & ~(size_t)255;
    return p;
  };
  short* RB      = (short*)alloc((size_t)2048 * 64 * 2);
  unsigned* PMAX = (unsigned*)alloc(256);
  short* XB      = (short*)alloc((size_t)MR * CC * 2);
  short* WQT     = (short*)alloc((size_t)NQK * CC * 2);
  short* WKT     = (short*)alloc((size_t)NQK * CC * 2);
  short* WVT     = (short*)alloc((size_t)NVD * CC * 2);
  short* WOT     = (short*)alloc((size_t)CC * NVD * 2);
  short* QP      = (short*)alloc((size_t)MR * NQK * 2);
  short* QS      = (short*)alloc((size_t)MR * NQK * 2);
  short* KB      = (short*)alloc((size_t)MR * NQK * 2);
  short* VB      = (short*)alloc((size_t)MR * NVD * 2);
  short* VT      = (short*)alloc((size_t)MR * NVD * 2);
  short* AO      = (short*)alloc((size_t)MR * NVD * 2);

  hipMemsetAsync(PMAX, 0, 4, stream);
  k_f32_to_bf16<<<2048, 256, 0, stream>>>(x, XB, MR * CC);
  k_transpose_w<<<dim3(NQK / 32, CC / 32), dim3(32, 8), 0, stream>>>(Wq, WQT, CC, NQK);
  k_transpose_w<<<dim3(NQK / 32, CC / 32), dim3(32, 8), 0, stream>>>(Wk, WKT, CC, NQK);
  k_transpose_w<<<dim3(NVD / 32, CC / 32), dim3(32, 8), 0, stream>>>(Wv, WVT, CC, NVD);
  k_transpose_w<<<dim3(CC / 32, NVD / 32), dim3(32, 8), 0, stream>>>(Wo, WOT, NVD, CC);
  k_pdfmax<<<64, 256, 0, stream>>>(PMAX);
  k_build_r<<<2048, 256, 0, stream>>>(WR, PMAX, RB);
  k_gemm<1><<<dim3(MR / 128, NQK / 128), 256, 0, stream>>>(XB, WQT, MR, NQK, CC, bq, uu, QS, QP);
  k_gemm<0><<<dim3(MR / 128, NQK / 128), 256, 0, stream>>>(XB, WKT, MR, NQK, CC, bk, nullptr, KB, nullptr);
  k_gemm<0><<<dim3(MR / 128, NVD / 128), 256, 0, stream>>>(XB, WVT, MR, NVD, CC, bv, nullptr, VB, nullptr);
  k_transpose_v<<<dim3(LL / 32, VDIM / 32, BB * HH), dim3(32, 8), 0, stream>>>(VB, VT);
  k_attn<<<dim3(LL / 64 * BB * HH), 256, 0, stream>>>(QP, QS, KB, VT, RB, AO);
  k_gemm<2><<<dim3(MR / 128, CC / 128), 256, 0, stream>>>(AO, WOT, MR, CC, NVD, bo, nullptr, d_out, nullptr);
}

// Round 4
// 377.568 us; speedup vs baseline: 1.3803x; 1.3803x over previous
//
#include <hip/hip_runtime.h>
#include <cstdint>
#include <cstddef>

typedef float f32x4 __attribute__((ext_vector_type(4)));
typedef short bf16x8 __attribute__((ext_vector_type(8)));

#define DEVI __device__ __forceinline__

namespace {

constexpr int BB = 8, LL = 1024, CC = 1536;
constexpr int HH = 8, KDIM = 64, VDIM = 192;
constexpr int NFEAT = 192, FSZ = 32;
constexpr float SCL = 0.125f;
constexpr int MR = BB * LL;     // 8192
constexpr int NQK = HH * KDIM;  // 512
constexpr int NVD = HH * VDIM;  // 1536

DEVI short f2bf(float f) {
  unsigned u = __float_as_uint(f);
  u = (u + 0x7FFFu + ((u >> 16) & 1u)) >> 16;
  return (short)u;
}

DEVI void gload_lds16(const void* g, void* l) {
  __builtin_amdgcn_global_load_lds(
      (const __attribute__((address_space(1))) void*)g,
      (__attribute__((address_space(3))) void*)l, 16, 0, 0);
}

// ---------------- convert f32 -> bf16 ----------------
__global__ void k_f32_to_bf16(const float* __restrict__ src, short* __restrict__ dst, int n) {
  int i0 = (blockIdx.x * blockDim.x + threadIdx.x) * 4;
  int stride = gridDim.x * blockDim.x * 4;
  for (int i = i0; i < n; i += stride) {
    float4 v = *reinterpret_cast<const float4*>(src + i);
    short4 o = { f2bf(v.x), f2bf(v.y), f2bf(v.z), f2bf(v.w) };
    *reinterpret_cast<short4*>(dst + i) = o;
  }
}

// ---------------- transpose f32 [R][Cd] -> bf16 [Cd][R] ----------------
__global__ void k_transpose_w(const float* __restrict__ src, short* __restrict__ dst, int R, int Cd) {
  __shared__ float tile[32][33];
  int c0 = blockIdx.x * 32, r0 = blockIdx.y * 32;
  int tx = threadIdx.x, ty = threadIdx.y;   // (32, 8)
  #pragma unroll
  for (int i = 0; i < 4; i++)
    tile[ty + i * 8][tx] = src[(size_t)(r0 + ty + i * 8) * Cd + c0 + tx];
  __syncthreads();
  #pragma unroll
  for (int i = 0; i < 4; i++)
    dst[(size_t)(c0 + ty + i * 8) * R + r0 + tx] = f2bf(tile[tx][ty + i * 8]);
}

// ---------------- V: [8192][1536] bf16 -> Vt [64][192][1024] bf16 ----------------
__global__ void k_transpose_v(const short* __restrict__ vb, short* __restrict__ vt) {
  __shared__ short tile[32][33];
  int bh = blockIdx.z;
  int b = bh >> 3, h = bh & 7;
  int v0 = blockIdx.y * 32;
  int s0 = blockIdx.x * 32;
  int tx = threadIdx.x, ty = threadIdx.y;
  #pragma unroll
  for (int i = 0; i < 4; i++)
    tile[ty + i * 8][tx] = vb[(size_t)(b * LL + s0 + ty + i * 8) * NVD + h * VDIM + v0 + tx];
  __syncthreads();
  #pragma unroll
  for (int i = 0; i < 4; i++)
    vt[(size_t)bh * VDIM * LL + (size_t)(v0 + ty + i * 8) * LL + s0 + tx] = tile[tx][ty + i * 8];
}

// ---------------- gamma pdf global max ----------------
__global__ void k_pdfmax(unsigned* slot) {
  int tid = blockIdx.x * blockDim.x + threadIdx.x;
  int nth = gridDim.x * blockDim.x;
  double lmax = 0.0;
  for (int idx = tid; idx < 2047 * FSZ; idx += nth) {
    int j = idx >> 5, i = idx & 31;
    double ap = (double)(j >= 1023 ? j - 1023 : 1023 - j);
    double mean = 32.0 + 32.0 * (double)i;
    double conc = (mean * (1.0 / 16.0)) * (mean * (1.0 / 16.0));
    double rate = mean * (1.0 / 256.0);
    double lp = (conc - 1.0) * log(ap) - rate * ap - lgamma(conc) + conc * log(rate);
    double pdf = exp(lp) + 1e-8;
    lmax = fmax(lmax, pdf);
  }
  float fv = (float)lmax;
  #pragma unroll
  for (int o = 32; o > 0; o >>= 1) fv = fmaxf(fv, __shfl_down(fv, o, 64));
  if ((threadIdx.x & 63) == 0) atomicMax(slot, __float_as_uint(fv));
}

// ---------------- build RB: row 0 = zeros, row j+1 = (basis[j] @ WR) ----------------
__global__ void k_build_r(const float* __restrict__ WR, const unsigned* __restrict__ slot,
                          short* __restrict__ rbuf) {
  __shared__ float feats[NFEAT];
  int jp = blockIdx.x;       // 0..2047
  int tid = threadIdx.x;     // 256
  if (jp == 0) {
    if (tid < KDIM) rbuf[tid] = 0;
    return;
  }
  int j = jp - 1;            // 0..2046
  int pos = j - (LL - 1);
  int api = pos < 0 ? -pos : pos;
  double ap = (double)api;
  float sgn = pos > 0 ? 1.0f : (pos < 0 ? -1.0f : 0.0f);
  if (tid < FSZ) {
    double xhl = 3.0 + 7.0 * (double)tid / 31.0;
    double hl = exp2(xhl);
    float fe = (float)exp2(-ap / hl);
    feats[tid] = fe; feats[FSZ + tid] = sgn * fe;
  } else if (tid < 2 * FSZ) {
    int i = tid - FSZ;
    double cw = exp2((double)(i + 1)) - 1.0;
    float fc = cw > ap ? 1.0f : 0.0f;
    feats[2 * FSZ + i] = fc; feats[3 * FSZ + i] = sgn * fc;
  } else if (tid < 3 * FSZ) {
    int i = tid - 2 * FSZ;
    double mean = 32.0 + 32.0 * (double)i;
    double conc = (mean * (1.0 / 16.0)) * (mean * (1.0 / 16.0));
    double rate = mean * (1.0 / 256.0);
    double lp = (conc - 1.0) * log(ap) - rate * ap - lgamma(conc) + conc * log(rate);
    double pdf = exp(lp) + 1e-8;
    float fg = (float)(pdf / (double)__uint_as_float(*slot));
    feats[4 * FSZ + i] = fg; feats[5 * FSZ + i] = sgn * fg;
  }
  __syncthreads();
  if (tid < KDIM) {
    float acc = 0.f;
    #pragma unroll 4
    for (int f = 0; f < NFEAT; f++) acc += feats[f] * WR[f * KDIM + tid];
    rbuf[jp * KDIM + tid] = f2bf(acc);
  }
}

// ---------------- bf16 MFMA GEMM: C = A[M,K] @ Bt[N,K]^T + bias ----------------
// MODE 0: bf16 store to D0.  MODE 1: D0=(val)*SCL bf16, D1=(val+bias2)*SCL bf16.  MODE 2: f32 store.
template<int MODE>
__global__ __launch_bounds__(256, 2)
void k_gemm(const short* __restrict__ A, const short* __restrict__ Bt,
            int Mdim, int Ndim, int Kdim,
            const float* __restrict__ bias, const float* __restrict__ bias2,
            void* __restrict__ D0, void* __restrict__ D1) {
  __shared__ short As[128][64];
  __shared__ short Bs[128][64];
  int m0 = blockIdx.x * 128, n0 = blockIdx.y * 128;
  int tid = threadIdx.x;
  int w = tid >> 6, l = tid & 63;
  int wr = (w >> 1) * 64, wc = (w & 1) * 64;

  f32x4 acc[4][4] = {};

  const short* ga = A + (size_t)(m0 + w * 8 + (l >> 3)) * Kdim + (l & 7) * 8;
  const short* gb = Bt + (size_t)(n0 + w * 8 + (l >> 3)) * Kdim + (l & 7) * 8;

  for (int k0 = 0; k0 < Kdim; k0 += 64) {
    #pragma unroll
    for (int i = 0; i < 4; i++) {
      gload_lds16(ga + (size_t)(i * 32) * Kdim + k0, &As[i * 32 + w * 8][0]);
      gload_lds16(gb + (size_t)(i * 32) * Kdim + k0, &Bs[i * 32 + w * 8][0]);
    }
    __syncthreads();
    #pragma unroll
    for (int kk = 0; kk < 2; kk++) {
      bf16x8 af[4], bfr[4];
      #pragma unroll
      for (int mi = 0; mi < 4; mi++)
        af[mi] = *(const bf16x8*)&As[wr + mi * 16 + (l & 15)][kk * 32 + (l >> 4) * 8];
      #pragma unroll
      for (int ni = 0; ni < 4; ni++)
        bfr[ni] = *(const bf16x8*)&Bs[wc + ni * 16 + (l & 15)][kk * 32 + (l >> 4) * 8];
      #pragma unroll
      for (int mi = 0; mi < 4; mi++)
        #pragma unroll
        for (int ni = 0; ni < 4; ni++)
          acc[mi][ni] = __builtin_amdgcn_mfma_f32_16x16x32_bf16(af[mi], bfr[ni], acc[mi][ni], 0, 0, 0);
    }
    __syncthreads();
  }

  int lr = (l >> 4) * 4, lc = l & 15;
  #pragma unroll
  for (int ni = 0; ni < 4; ni++) {
    int col = n0 + wc + ni * 16 + lc;
    float bvv = bias[col];
    float bv2 = (MODE == 1) ? bias2[col] : 0.f;
    #pragma unroll
    for (int mi = 0; mi < 4; mi++) {
      #pragma unroll
      for (int r = 0; r < 4; r++) {
        int row = m0 + wr + mi * 16 + lr + r;
        float val = acc[mi][ni][r] + bvv;
        if (MODE == 0) {
          ((short*)D0)[(size_t)row * Ndim + col] = f2bf(val);
        } else if (MODE == 1) {
          ((short*)D0)[(size_t)row * Ndim + col] = f2bf(val * SCL);
          ((short*)D1)[(size_t)row * Ndim + col] = f2bf((val + bv2) * SCL);
        } else {
          ((float*)D0)[(size_t)row * Ndim + col] = val;
        }
      }
    }
  }
}

// ---------------- flash attention: 128q block, 4 waves x 32q, async-staged ----------------
// Parity q-ownership: w0 even rows 0..62, w1 even 64..126, w2 odd 1..63, w3 odd 65..127
// -> wave-uniform RB base for the rel-shift term. Q in registers; K,V^T staged
// in LDS with async split (issue loads before compute, ds_write after barrier);
// RB B-frags direct from global (L2-hot, batched); softmax fully in-register
// (acc rows == owned q rows so rescale factor is lane-local); P via wave-private
// LDS slice (no barrier, validated R3). 2 barriers per k-tile.
__global__ __launch_bounds__(256, 2)
void k_attn(const short* __restrict__ Qp, const short* __restrict__ Qs,
            const short* __restrict__ Kb, const short* __restrict__ Vt,
            const short* __restrict__ Rb, short* __restrict__ AO) {
  __shared__ short sK[64][72];
  __shared__ short sV[192][72];
  __shared__ short sP[128][72];   // wave w: rows [w*32, w*32+32), private

  int bid = blockIdx.x;
  int swz = (bid & 7) * 64 + (bid >> 3);   // XCD-contiguous bh
  int qt = swz & 7, bh = swz >> 3;
  int b = bh >> 3, h = bh & 7;
  int q0 = qt * 128;
  int tid = threadIdx.x;
  int w = tid >> 6, l = tid & 63;
  int hi = l >> 4, lc = l & 15;

  int base = (w & 1) * 64;        // q sub-block within the 128
  int par = w >> 1;               // 0: even rows, 1: odd rows
  int rbase = par ? 0 : 1024;     // RB slice for this parity

  // A-fragments in registers.
  bf16x8 aq1[2][2], aq2[2][2];
  #pragma unroll
  for (int mi = 0; mi < 2; mi++) {
    int qglob = q0 + base + par + 2 * (mi * 16 + lc);
    const short* qpg = Qp + (size_t)(b * LL + qglob) * NQK + h * KDIM;
    aq1[mi][0] = *(const bf16x8*)&qpg[hi * 8];
    aq1[mi][1] = *(const bf16x8*)&qpg[32 + hi * 8];
    int qsrow = q0 / 2 + base / 2 + par + mi * 16 + lc;
    const short* qsg = Qs + (size_t)(b * LL + qsrow) * NQK + h * KDIM;
    aq2[mi][0] = *(const bf16x8*)&qsg[hi * 8];
    aq2[mi][1] = *(const bf16x8*)&qsg[32 + hi * 8];
  }

  const short* kg = Kb + (size_t)(b * LL) * NQK + h * KDIM;
  const short* vg = Vt + (size_t)bh * VDIM * LL;
  const short* rg = Rb + (size_t)rbase * KDIM;

  float mrun[2][4], lrun[2][4];
  #pragma unroll
  for (int mi = 0; mi < 2; mi++)
    #pragma unroll
    for (int r = 0; r < 4; r++) { mrun[mi][r] = -INFINITY; lrun[mi][r] = 0.f; }
  f32x4 oacc[2][12] = {};

  // prologue: stage tile 0
  {
    uint4 kr[2], vr[6];
    #pragma unroll
    for (int j = 0; j < 2; j++) {
      int flat = j * 256 + tid, r = flat >> 3, c = (flat & 7) * 8;
      kr[j] = *(const uint4*)&kg[(size_t)r * NQK + c];
    }
    #pragma unroll
    for (int j = 0; j < 6; j++) {
      int flat = j * 256 + tid, r = flat >> 3, c = (flat & 7) * 8;
      vr[j] = *(const uint4*)&vg[(size_t)r * LL + c];
    }
    #pragma unroll
    for (int j = 0; j < 2; j++) {
      int flat = j * 256 + tid, r = flat >> 3, c = (flat & 7) * 8;
      *(uint4*)&sK[r][c] = kr[j];
    }
    #pragma unroll
    for (int j = 0; j < 6; j++) {
      int flat = j * 256 + tid, r = flat >> 3, c = (flat & 7) * 8;
      *(uint4*)&sV[r][c] = vr[j];
    }
  }
  __syncthreads();

  for (int t = 0; t < 16; t++) {
    int k0 = t * 64;
    bool more = (t < 15);

    // T14: issue next tile's global loads now; write after post-PV barrier.
    uint4 kr[2], vr[6];
    if (more) {
      int kn = k0 + 64;
      #pragma unroll
      for (int j = 0; j < 2; j++) {
        int flat = j * 256 + tid, r = flat >> 3, c = (flat & 7) * 8;
        kr[j] = *(const uint4*)&kg[(size_t)(kn + r) * NQK + c];
      }
      #pragma unroll
      for (int j = 0; j < 6; j++) {
        int flat = j * 256 + tid, r = flat >> 3, c = (flat & 7) * 8;
        vr[j] = *(const uint4*)&vg[(size_t)r * LL + kn + c];
      }
    }

    // batch-load RB B-frags (global, L2-hot)
    bf16x8 br[2][4];
    #pragma unroll
    for (int kk = 0; kk < 2; kk++)
      #pragma unroll
      for (int ni = 0; ni < 4; ni++)
        br[kk][ni] = *(const bf16x8*)&rg[(size_t)(k0 + ni * 16 + lc) * KDIM + kk * 32 + hi * 8];

    // scores: S1 (K from LDS) + S2 (RB from regs)
    f32x4 s[2][4] = {};
    #pragma unroll
    for (int kk = 0; kk < 2; kk++) {
      #pragma unroll
      for (int ni = 0; ni < 4; ni++) {
        bf16x8 bk = *(const bf16x8*)&sK[ni * 16 + lc][kk * 32 + hi * 8];
        #pragma unroll
        for (int mi = 0; mi < 2; mi++) {
          s[mi][ni] = __builtin_amdgcn_mfma_f32_16x16x32_bf16(aq1[mi][kk], bk, s[mi][ni], 0, 0, 0);
          s[mi][ni] = __builtin_amdgcn_mfma_f32_16x16x32_bf16(aq2[mi][kk], br[kk][ni], s[mi][ni], 0, 0, 0);
        }
      }
    }

    // in-register online softmax; P -> wave-private LDS slice
    float fac[2][4];
    #pragma unroll
    for (int mi = 0; mi < 2; mi++) {
      #pragma unroll
      for (int r = 0; r < 4; r++) {
        float mx = fmaxf(fmaxf(s[mi][0][r], s[mi][1][r]), fmaxf(s[mi][2][r], s[mi][3][r]));
        mx = fmaxf(mx, __shfl_xor(mx, 1, 64));
        mx = fmaxf(mx, __shfl_xor(mx, 2, 64));
        mx = fmaxf(mx, __shfl_xor(mx, 4, 64));
        mx = fmaxf(mx, __shfl_xor(mx, 8, 64));
        float mnew = fmaxf(mrun[mi][r], mx);
        float fc = __expf(mrun[mi][r] - mnew);
        mrun[mi][r] = mnew;
        fac[mi][r] = fc;
        float ps = 0.f;
        int prow = w * 32 + mi * 16 + 4 * hi + r;
        #pragma unroll
        for (int ni = 0; ni < 4; ni++) {
          float p = __expf(s[mi][ni][r] - mnew);
          ps += p;
          sP[prow][ni * 16 + lc] = f2bf(p);
        }
        ps += __shfl_xor(ps, 1, 64);
        ps += __shfl_xor(ps, 2, 64);
        ps += __shfl_xor(ps, 4, 64);
        ps += __shfl_xor(ps, 8, 64);
        lrun[mi][r] = lrun[mi][r] * fc + ps;
      }
    }

    // rescale O (factor is lane-local: acc rows == owned q rows)
    #pragma unroll
    for (int mi = 0; mi < 2; mi++)
      #pragma unroll
      for (int ni = 0; ni < 12; ni++)
        #pragma unroll
        for (int r = 0; r < 4; r++)
          oacc[mi][ni][r] *= fac[mi][r];

    // PV: A = own P rows (wave-private LDS), B = V^T cols from LDS
    #pragma unroll
    for (int kk = 0; kk < 2; kk++) {
      bf16x8 pa[2];
      #pragma unroll
      for (int mi = 0; mi < 2; mi++)
        pa[mi] = *(const bf16x8*)&sP[w * 32 + mi * 16 + lc][kk * 32 + hi * 8];
      #pragma unroll
      for (int ni = 0; ni < 12; ni++) {
        bf16x8 bv = *(const bf16x8*)&sV[ni * 16 + lc][kk * 32 + hi * 8];
        #pragma unroll
        for (int mi = 0; mi < 2; mi++)
          oacc[mi][ni] = __builtin_amdgcn_mfma_f32_16x16x32_bf16(pa[mi], bv, oacc[mi][ni], 0, 0, 0);
      }
    }

    if (more) {
      __syncthreads();   // all waves done reading sK/sV for tile t
      #pragma unroll
      for (int j = 0; j < 2; j++) {
        int flat = j * 256 + tid, r = flat >> 3, c = (flat & 7) * 8;
        *(uint4*)&sK[r][c] = kr[j];
      }
      #pragma unroll
      for (int j = 0; j < 6; j++) {
        int flat = j * 256 + tid, r = flat >> 3, c = (flat & 7) * 8;
        *(uint4*)&sV[r][c] = vr[j];
      }
      __syncthreads();   // staged tile t+1 visible
    }
  }

  // epilogue: normalize and store (factors lane-local)
  #pragma unroll
  for (int mi = 0; mi < 2; mi++) {
    #pragma unroll
    for (int r = 0; r < 4; r++) {
      float iv = 1.0f / lrun[mi][r];
      int qglob = q0 + base + par + 2 * (mi * 16 + 4 * hi + r);
      short* ao = AO + (size_t)(b * LL + qglob) * NVD + h * VDIM;
      #pragma unroll
      for (int ni = 0; ni < 12; ni++)
        ao[ni * 16 + lc] = f2bf(oacc[mi][ni][r] * iv);
    }
  }
}

}  // namespace

extern "C" void kernel_launch(void* const* d_in, const int* in_sizes, int n_in,
                              void* d_out, int out_size, void* d_ws, size_t ws_size,
                              hipStream_t stream) {
  (void)in_sizes; (void)n_in; (void)out_size; (void)ws_size;
  const float* x  = (const float*)d_in[0];
  const float* Wq = (const float*)d_in[1];
  const float* bq = (const float*)d_in[2];
  const float* Wk = (const float*)d_in[3];
  const float* bk = (const float*)d_in[4];
  const float* Wv = (const float*)d_in[5];
  const float* bv = (const float*)d_in[6];
  const float* Wo = (const float*)d_in[7];
  const float* bo = (const float*)d_in[8];
  const float* WR = (const float*)d_in[9];
  const float* uu = (const float*)d_in[10];
  // d_in[11] (v) intentionally unused: term4 is constant along the softmax axis.

  char* ws = (char*)d_ws;
  size_t off = 0;
  auto alloc = [&](size_t bytes) -> void* {
    void* p = ws + off;
    off += (bytes + 255) & ~(size_t)255;
    return p;
  };
  short* RB      = (short*)alloc((size_t)2048 * 64 * 2);
  unsigned* PMAX = (unsigned*)alloc(256);
  short* XB      = (short*)alloc((size_t)MR * CC * 2);
  short* WQT     = (short*)alloc((size_t)NQK * CC * 2);
  short* WKT     = (short*)alloc((size_t)NQK * CC * 2);
  short* WVT     = (short*)alloc((size_t)NVD * CC * 2);
  short* WOT     = (short*)alloc((size_t)CC * NVD * 2);
  short* QP      = (short*)alloc((size_t)MR * NQK * 2);
  short* QS      = (short*)alloc((size_t)MR * NQK * 2);
  short* KB      = (short*)alloc((size_t)MR * NQK * 2);
  short* VB      = (short*)alloc((size_t)MR * NVD * 2);
  short* VT      = (short*)alloc((size_t)MR * NVD * 2);
  short* AO      = (short*)alloc((size_t)MR * NVD * 2);

  hipMemsetAsync(PMAX, 0, 4, stream);
  k_f32_to_bf16<<<2048, 256, 0, stream>>>(x, XB, MR * CC);
  k_transpose_w<<<dim3(NQK / 32, CC / 32), dim3(32, 8), 0, stream>>>(Wq, WQT, CC, NQK);
  k_transpose_w<<<dim3(NQK / 32, CC / 32), dim3(32, 8), 0, stream>>>(Wk, WKT, CC, NQK);
  k_transpose_w<<<dim3(NVD / 32, CC / 32), dim3(32, 8), 0, stream>>>(Wv, WVT, CC, NVD);
  k_transpose_w<<<dim3(CC / 32, NVD / 32), dim3(32, 8), 0, stream>>>(Wo, WOT, NVD, CC);
  k_pdfmax<<<64, 256, 0, stream>>>(PMAX);
  k_build_r<<<2048, 256, 0, stream>>>(WR, PMAX, RB);
  k_gemm<1><<<dim3(MR / 128, NQK / 128), 256, 0, stream>>>(XB, WQT, MR, NQK, CC, bq, uu, QS, QP);
  k_gemm<0><<<dim3(MR / 128, NQK / 128), 256, 0, stream>>>(XB, WKT, MR, NQK, CC, bk, nullptr, KB, nullptr);
  k_gemm<0><<<dim3(MR / 128, NVD / 128), 256, 0, stream>>>(XB, WVT, MR, NVD, CC, bv, nullptr, VB, nullptr);
  k_transpose_v<<<dim3(LL / 32, VDIM / 32, BB * HH), dim3(32, 8), 0, stream>>>(VB, VT);
  k_attn<<<dim3(LL / 128 * BB * HH), 256, 0, stream>>>(QP, QS, KB, VT, RB, AO);
  k_gemm<2><<<dim3(MR / 128, CC / 128), 256, 0, stream>>>(AO, WOT, MR, CC, NVD, bo, nullptr, d_out, nullptr);
}

// Round 5
// 324.423 us; speedup vs baseline: 1.6064x; 1.1638x over previous
//
#include <hip/hip_runtime.h>
#include <cstdint>
#include <cstddef>

typedef float f32x4 __attribute__((ext_vector_type(4)));
typedef short bf16x8 __attribute__((ext_vector_type(8)));

#define DEVI __device__ __forceinline__

namespace {

constexpr int BB = 8, LL = 1024, CC = 1536;
constexpr int HH = 8, KDIM = 64, VDIM = 192;
constexpr int NFEAT = 192, FSZ = 32;
constexpr float SCL = 0.125f;
constexpr int MR = BB * LL;     // 8192
constexpr int NQK = HH * KDIM;  // 512
constexpr int NVD = HH * VDIM;  // 1536

DEVI short f2bf(float f) {
  unsigned u = __float_as_uint(f);
  u = (u + 0x7FFFu + ((u >> 16) & 1u)) >> 16;
  return (short)u;
}

DEVI void gload_lds16(const void* g, void* l) {
  __builtin_amdgcn_global_load_lds(
      (const __attribute__((address_space(1))) void*)g,
      (__attribute__((address_space(3))) void*)l, 16, 0, 0);
}

// ---------------- convert f32 -> bf16 ----------------
__global__ void k_f32_to_bf16(const float* __restrict__ src, short* __restrict__ dst, int n) {
  int i0 = (blockIdx.x * blockDim.x + threadIdx.x) * 4;
  int stride = gridDim.x * blockDim.x * 4;
  for (int i = i0; i < n; i += stride) {
    float4 v = *reinterpret_cast<const float4*>(src + i);
    short4 o = { f2bf(v.x), f2bf(v.y), f2bf(v.z), f2bf(v.w) };
    *reinterpret_cast<short4*>(dst + i) = o;
  }
}

// ---------------- transpose f32 [R][Cd] -> bf16 [Cd][R] ----------------
__global__ void k_transpose_w(const float* __restrict__ src, short* __restrict__ dst, int R, int Cd) {
  __shared__ float tile[32][33];
  int c0 = blockIdx.x * 32, r0 = blockIdx.y * 32;
  int tx = threadIdx.x, ty = threadIdx.y;   // (32, 8)
  #pragma unroll
  for (int i = 0; i < 4; i++)
    tile[ty + i * 8][tx] = src[(size_t)(r0 + ty + i * 8) * Cd + c0 + tx];
  __syncthreads();
  #pragma unroll
  for (int i = 0; i < 4; i++)
    dst[(size_t)(c0 + ty + i * 8) * R + r0 + tx] = f2bf(tile[tx][ty + i * 8]);
}

// ---------------- V: [8192][1536] bf16 -> Vt [64][192][1024] bf16 ----------------
__global__ void k_transpose_v(const short* __restrict__ vb, short* __restrict__ vt) {
  __shared__ short tile[32][33];
  int bh = blockIdx.z;
  int b = bh >> 3, h = bh & 7;
  int v0 = blockIdx.y * 32;
  int s0 = blockIdx.x * 32;
  int tx = threadIdx.x, ty = threadIdx.y;
  #pragma unroll
  for (int i = 0; i < 4; i++)
    tile[ty + i * 8][tx] = vb[(size_t)(b * LL + s0 + ty + i * 8) * NVD + h * VDIM + v0 + tx];
  __syncthreads();
  #pragma unroll
  for (int i = 0; i < 4; i++)
    vt[(size_t)bh * VDIM * LL + (size_t)(v0 + ty + i * 8) * LL + s0 + tx] = tile[tx][ty + i * 8];
}

// ---------------- gamma pdf global max ----------------
__global__ void k_pdfmax(unsigned* slot) {
  int tid = blockIdx.x * blockDim.x + threadIdx.x;
  int nth = gridDim.x * blockDim.x;
  double lmax = 0.0;
  for (int idx = tid; idx < 2047 * FSZ; idx += nth) {
    int j = idx >> 5, i = idx & 31;
    double ap = (double)(j >= 1023 ? j - 1023 : 1023 - j);
    double mean = 32.0 + 32.0 * (double)i;
    double conc = (mean * (1.0 / 16.0)) * (mean * (1.0 / 16.0));
    double rate = mean * (1.0 / 256.0);
    double lp = (conc - 1.0) * log(ap) - rate * ap - lgamma(conc) + conc * log(rate);
    double pdf = exp(lp) + 1e-8;
    lmax = fmax(lmax, pdf);
  }
  float fv = (float)lmax;
  #pragma unroll
  for (int o = 32; o > 0; o >>= 1) fv = fmaxf(fv, __shfl_down(fv, o, 64));
  if ((threadIdx.x & 63) == 0) atomicMax(slot, __float_as_uint(fv));
}

// ---------------- build RB: row 0 = zeros, row j+1 = (basis[j] @ WR) ----------------
__global__ void k_build_r(const float* __restrict__ WR, const unsigned* __restrict__ slot,
                          short* __restrict__ rbuf) {
  __shared__ float feats[NFEAT];
  int jp = blockIdx.x;       // 0..2047
  int tid = threadIdx.x;     // 256
  if (jp == 0) {
    if (tid < KDIM) rbuf[tid] = 0;
    return;
  }
  int j = jp - 1;            // 0..2046
  int pos = j - (LL - 1);
  int api = pos < 0 ? -pos : pos;
  double ap = (double)api;
  float sgn = pos > 0 ? 1.0f : (pos < 0 ? -1.0f : 0.0f);
  if (tid < FSZ) {
    double xhl = 3.0 + 7.0 * (double)tid / 31.0;
    double hl = exp2(xhl);
    float fe = (float)exp2(-ap / hl);
    feats[tid] = fe; feats[FSZ + tid] = sgn * fe;
  } else if (tid < 2 * FSZ) {
    int i = tid - FSZ;
    double cw = exp2((double)(i + 1)) - 1.0;
    float fc = cw > ap ? 1.0f : 0.0f;
    feats[2 * FSZ + i] = fc; feats[3 * FSZ + i] = sgn * fc;
  } else if (tid < 3 * FSZ) {
    int i = tid - 2 * FSZ;
    double mean = 32.0 + 32.0 * (double)i;
    double conc = (mean * (1.0 / 16.0)) * (mean * (1.0 / 16.0));
    double rate = mean * (1.0 / 256.0);
    double lp = (conc - 1.0) * log(ap) - rate * ap - lgamma(conc) + conc * log(rate);
    double pdf = exp(lp) + 1e-8;
    float fg = (float)(pdf / (double)__uint_as_float(*slot));
    feats[4 * FSZ + i] = fg; feats[5 * FSZ + i] = sgn * fg;
  }
  __syncthreads();
  if (tid < KDIM) {
    float acc = 0.f;
    #pragma unroll 4
    for (int f = 0; f < NFEAT; f++) acc += feats[f] * WR[f * KDIM + tid];
    rbuf[jp * KDIM + tid] = f2bf(acc);
  }
}

// ---------------- bf16 MFMA GEMM: C = A[M,K] @ Bt[N,K]^T + bias ----------------
// MODE 0: bf16 store to D0.  MODE 1: D0=(val)*SCL bf16, D1=(val+bias2)*SCL bf16.  MODE 2: f32 store.
template<int MODE>
__global__ __launch_bounds__(256, 2)
void k_gemm(const short* __restrict__ A, const short* __restrict__ Bt,
            int Mdim, int Ndim, int Kdim,
            const float* __restrict__ bias, const float* __restrict__ bias2,
            void* __restrict__ D0, void* __restrict__ D1) {
  __shared__ short As[128][64];
  __shared__ short Bs[128][64];
  int m0 = blockIdx.x * 128, n0 = blockIdx.y * 128;
  int tid = threadIdx.x;
  int w = tid >> 6, l = tid & 63;
  int wr = (w >> 1) * 64, wc = (w & 1) * 64;

  f32x4 acc[4][4] = {};

  const short* ga = A + (size_t)(m0 + w * 8 + (l >> 3)) * Kdim + (l & 7) * 8;
  const short* gb = Bt + (size_t)(n0 + w * 8 + (l >> 3)) * Kdim + (l & 7) * 8;

  for (int k0 = 0; k0 < Kdim; k0 += 64) {
    #pragma unroll
    for (int i = 0; i < 4; i++) {
      gload_lds16(ga + (size_t)(i * 32) * Kdim + k0, &As[i * 32 + w * 8][0]);
      gload_lds16(gb + (size_t)(i * 32) * Kdim + k0, &Bs[i * 32 + w * 8][0]);
    }
    __syncthreads();
    #pragma unroll
    for (int kk = 0; kk < 2; kk++) {
      bf16x8 af[4], bfr[4];
      #pragma unroll
      for (int mi = 0; mi < 4; mi++)
        af[mi] = *(const bf16x8*)&As[wr + mi * 16 + (l & 15)][kk * 32 + (l >> 4) * 8];
      #pragma unroll
      for (int ni = 0; ni < 4; ni++)
        bfr[ni] = *(const bf16x8*)&Bs[wc + ni * 16 + (l & 15)][kk * 32 + (l >> 4) * 8];
      #pragma unroll
      for (int mi = 0; mi < 4; mi++)
        #pragma unroll
        for (int ni = 0; ni < 4; ni++)
          acc[mi][ni] = __builtin_amdgcn_mfma_f32_16x16x32_bf16(af[mi], bfr[ni], acc[mi][ni], 0, 0, 0);
    }
    __syncthreads();
  }

  int lr = (l >> 4) * 4, lc = l & 15;
  #pragma unroll
  for (int ni = 0; ni < 4; ni++) {
    int col = n0 + wc + ni * 16 + lc;
    float bvv = bias[col];
    float bv2 = (MODE == 1) ? bias2[col] : 0.f;
    #pragma unroll
    for (int mi = 0; mi < 4; mi++) {
      #pragma unroll
      for (int r = 0; r < 4; r++) {
        int row = m0 + wr + mi * 16 + lr + r;
        float val = acc[mi][ni][r] + bvv;
        if (MODE == 0) {
          ((short*)D0)[(size_t)row * Ndim + col] = f2bf(val);
        } else if (MODE == 1) {
          ((short*)D0)[(size_t)row * Ndim + col] = f2bf(val * SCL);
          ((short*)D1)[(size_t)row * Ndim + col] = f2bf((val + bv2) * SCL);
        } else {
          ((float*)D0)[(size_t)row * Ndim + col] = val;
        }
      }
    }
  }
}

// ---------------- flash attention: 128q/block, gload_lds dbuf, 1 barrier/tile ----------------
// Parity q-ownership (wave-uniform RB base). K/V staged via global_load_lds into
// LINEAR LDS with inverse-swizzled GLOBAL source; reads XOR-swizzled (rule #21)
// -> conflict-free b128 frags. P transposed via swizzled wave-private LDS slice.
// In-register online softmax + T13 defer-max. One __syncthreads per k-tile.
__global__ __launch_bounds__(256, 2)
void k_attn(const short* __restrict__ Qp, const short* __restrict__ Qs,
            const short* __restrict__ Kb, const short* __restrict__ Vt,
            const short* __restrict__ Rb, short* __restrict__ AO) {
  __shared__ short sK[2][64][64];
  __shared__ short sV[2][192][64];
  __shared__ short sP[128][64];

  int bid = blockIdx.x;
  int swz = (bid & 7) * 64 + (bid >> 3);   // XCD-contiguous bh
  int qt = swz & 7, bh = swz >> 3;
  int b = bh >> 3, h = bh & 7;
  int q0 = qt * 128;
  int tid = threadIdx.x;
  int w = tid >> 6, l = tid & 63;
  int hi = l >> 4, lc = l & 15;

  int base = (w & 1) * 64;        // q sub-block within the 128
  int par = w >> 1;               // 0: even rows, 1: odd rows
  int rbase = par ? 0 : 1024;     // RB slice for this parity

  // Q A-fragments in registers.
  bf16x8 aq1[2][2], aq2[2][2];
  #pragma unroll
  for (int mi = 0; mi < 2; mi++) {
    int qglob = q0 + base + par + 2 * (mi * 16 + lc);
    const short* qpg = Qp + (size_t)(b * LL + qglob) * NQK + h * KDIM;
    aq1[mi][0] = *(const bf16x8*)&qpg[hi * 8];
    aq1[mi][1] = *(const bf16x8*)&qpg[32 + hi * 8];
    int qsrow = q0 / 2 + base / 2 + par + mi * 16 + lc;
    const short* qsg = Qs + (size_t)(b * LL + qsrow) * NQK + h * KDIM;
    aq2[mi][0] = *(const bf16x8*)&qsg[hi * 8];
    aq2[mi][1] = *(const bf16x8*)&qsg[32 + hi * 8];
  }

  const short* kg = Kb + (size_t)(b * LL) * NQK + h * KDIM;
  const short* vg = Vt + (size_t)bh * VDIM * LL;
  const short* rg = Rb + (size_t)rbase * KDIM;

  // staging: per 8-row group, lane l covers row l>>3, chunk l&7 (16B units).
  // LDS is linear; the global source chunk is pre-swizzled: cg = (l&7) ^ (l>>3).
  int srow = l >> 3;
  int schunk = ((l & 7) ^ srow) * 8;   // element offset of fetched chunk

  float mrun[2][4], lrun[2][4];
  #pragma unroll
  for (int mi = 0; mi < 2; mi++)
    #pragma unroll
    for (int r = 0; r < 4; r++) { mrun[mi][r] = -INFINITY; lrun[mi][r] = 0.f; }
  f32x4 oacc[2][12] = {};

  // prologue: stage tile 0 into buffer 0
  #pragma unroll
  for (int j = 0; j < 2; j++) {
    int rb2 = (j * 4 + w) * 8;
    gload_lds16(kg + (size_t)(rb2 + srow) * NQK + schunk, &sK[0][rb2][0]);
  }
  #pragma unroll
  for (int j = 0; j < 6; j++) {
    int rb2 = (j * 4 + w) * 8;
    gload_lds16(vg + (size_t)(rb2 + srow) * LL + schunk, &sV[0][rb2][0]);
  }
  __syncthreads();

  int swzk = (lc & 7) << 3;   // read-side element XOR for rows with (row&7)==(lc&7)

  for (int t = 0; t < 16; t++) {
    int k0 = t * 64;
    int bf = t & 1;

    // stage next tile into the other buffer (drained by end-of-tile barrier)
    if (t < 15) {
      int kn = k0 + 64;
      #pragma unroll
      for (int j = 0; j < 2; j++) {
        int rb2 = (j * 4 + w) * 8;
        gload_lds16(kg + (size_t)(kn + rb2 + srow) * NQK + schunk, &sK[bf ^ 1][rb2][0]);
      }
      #pragma unroll
      for (int j = 0; j < 6; j++) {
        int rb2 = (j * 4 + w) * 8;
        gload_lds16(vg + (size_t)(rb2 + srow) * LL + kn + schunk, &sV[bf ^ 1][rb2][0]);
      }
    }

    // RB B-frags direct from global (L2-hot)
    bf16x8 br[2][4];
    #pragma unroll
    for (int kk = 0; kk < 2; kk++)
      #pragma unroll
      for (int ni = 0; ni < 4; ni++)
        br[kk][ni] = *(const bf16x8*)&rg[(size_t)(k0 + ni * 16 + lc) * KDIM + kk * 32 + hi * 8];

    // scores: S1 (K from LDS, swizzled read) + S2 (RB from regs)
    f32x4 s[2][4] = {};
    #pragma unroll
    for (int kk = 0; kk < 2; kk++) {
      #pragma unroll
      for (int ni = 0; ni < 4; ni++) {
        bf16x8 bk = *(const bf16x8*)&sK[bf][ni * 16 + lc][(kk * 32 + hi * 8) ^ swzk];
        #pragma unroll
        for (int mi = 0; mi < 2; mi++) {
          s[mi][ni] = __builtin_amdgcn_mfma_f32_16x16x32_bf16(aq1[mi][kk], bk, s[mi][ni], 0, 0, 0);
          s[mi][ni] = __builtin_amdgcn_mfma_f32_16x16x32_bf16(aq2[mi][kk], br[kk][ni], s[mi][ni], 0, 0, 0);
        }
      }
    }

    // row maxes (acc rows are owned q rows -> lane-local)
    float mx[2][4], fac[2][4];
    float dmax = -INFINITY;
    #pragma unroll
    for (int mi = 0; mi < 2; mi++) {
      #pragma unroll
      for (int r = 0; r < 4; r++) {
        float m3 = fmaxf(fmaxf(s[mi][0][r], s[mi][1][r]), fmaxf(s[mi][2][r], s[mi][3][r]));
        m3 = fmaxf(m3, __shfl_xor(m3, 1, 64));
        m3 = fmaxf(m3, __shfl_xor(m3, 2, 64));
        m3 = fmaxf(m3, __shfl_xor(m3, 4, 64));
        m3 = fmaxf(m3, __shfl_xor(m3, 8, 64));
        mx[mi][r] = m3;
        fac[mi][r] = 1.0f;
        dmax = fmaxf(dmax, m3 - mrun[mi][r]);
      }
    }

    // T13 defer-max: rescale only if some row grew by > 8
    if (__any(dmax > 8.0f)) {
      #pragma unroll
      for (int mi = 0; mi < 2; mi++)
        #pragma unroll
        for (int r = 0; r < 4; r++) {
          float mnew = fmaxf(mrun[mi][r], mx[mi][r]);
          fac[mi][r] = __expf(mrun[mi][r] - mnew);
          mrun[mi][r] = mnew;
        }
      #pragma unroll
      for (int mi = 0; mi < 2; mi++)
        #pragma unroll
        for (int ni = 0; ni < 12; ni++)
          #pragma unroll
          for (int r = 0; r < 4; r++)
            oacc[mi][ni][r] *= fac[mi][r];
    }

    // exp + P write (swizzled wave-private slice) + lrun update
    #pragma unroll
    for (int mi = 0; mi < 2; mi++) {
      #pragma unroll
      for (int r = 0; r < 4; r++) {
        int prow = w * 32 + mi * 16 + 4 * hi + r;
        int pxor = ((4 * hi + r) & 7) << 3;
        float ps = 0.f;
        #pragma unroll
        for (int ni = 0; ni < 4; ni++) {
          float p = __expf(s[mi][ni][r] - mrun[mi][r]);
          ps += p;
          sP[prow][(ni * 16 + lc) ^ pxor] = f2bf(p);
        }
        ps += __shfl_xor(ps, 1, 64);
        ps += __shfl_xor(ps, 2, 64);
        ps += __shfl_xor(ps, 4, 64);
        ps += __shfl_xor(ps, 8, 64);
        lrun[mi][r] = lrun[mi][r] * fac[mi][r] + ps;
      }
    }

    // PV: A = own P rows (swizzled), B = V^T cols (swizzled)
    __builtin_amdgcn_s_setprio(1);
    #pragma unroll
    for (int kk = 0; kk < 2; kk++) {
      bf16x8 pa[2];
      #pragma unroll
      for (int mi = 0; mi < 2; mi++)
        pa[mi] = *(const bf16x8*)&sP[w * 32 + mi * 16 + lc][(kk * 32 + hi * 8) ^ swzk];
      #pragma unroll
      for (int ni = 0; ni < 12; ni++) {
        bf16x8 bv = *(const bf16x8*)&sV[bf][ni * 16 + lc][(kk * 32 + hi * 8) ^ swzk];
        #pragma unroll
        for (int mi = 0; mi < 2; mi++)
          oacc[mi][ni] = __builtin_amdgcn_mfma_f32_16x16x32_bf16(pa[mi], bv, oacc[mi][ni], 0, 0, 0);
      }
    }
    __builtin_amdgcn_s_setprio(0);

    __syncthreads();   // tile t done; staged tile t+1 drained & visible
  }

  // epilogue: normalize and store (factors lane-local)
  #pragma unroll
  for (int mi = 0; mi < 2; mi++) {
    #pragma unroll
    for (int r = 0; r < 4; r++) {
      float iv = 1.0f / lrun[mi][r];
      int qglob = q0 + base + par + 2 * (mi * 16 + 4 * hi + r);
      short* ao = AO + (size_t)(b * LL + qglob) * NVD + h * VDIM;
      #pragma unroll
      for (int ni = 0; ni < 12; ni++)
        ao[ni * 16 + lc] = f2bf(oacc[mi][ni][r] * iv);
    }
  }
}

}  // namespace

extern "C" void kernel_launch(void* const* d_in, const int* in_sizes, int n_in,
                              void* d_out, int out_size, void* d_ws, size_t ws_size,
                              hipStream_t stream) {
  (void)in_sizes; (void)n_in; (void)out_size; (void)ws_size;
  const float* x  = (const float*)d_in[0];
  const float* Wq = (const float*)d_in[1];
  const float* bq = (const float*)d_in[2];
  const float* Wk = (const float*)d_in[3];
  const float* bk = (const float*)d_in[4];
  const float* Wv = (const float*)d_in[5];
  const float* bv = (const float*)d_in[6];
  const float* Wo = (const float*)d_in[7];
  const float* bo = (const float*)d_in[8];
  const float* WR = (const float*)d_in[9];
  const float* uu = (const float*)d_in[10];
  // d_in[11] (v) intentionally unused: term4 is constant along the softmax axis.

  char* ws = (char*)d_ws;
  size_t off = 0;
  auto alloc = [&](size_t bytes) -> void* {
    void* p = ws + off;
    off += (bytes + 255) & ~(size_t)255;
    return p;
  };
  short* RB      = (short*)alloc((size_t)2048 * 64 * 2);
  unsigned* PMAX = (unsigned*)alloc(256);
  short* XB      = (short*)alloc((size_t)MR * CC * 2);
  short* WQT     = (short*)alloc((size_t)NQK * CC * 2);
  short* WKT     = (short*)alloc((size_t)NQK * CC * 2);
  short* WVT     = (short*)alloc((size_t)NVD * CC * 2);
  short* WOT     = (short*)alloc((size_t)CC * NVD * 2);
  short* QP      = (short*)alloc((size_t)MR * NQK * 2);
  short* QS      = (short*)alloc((size_t)MR * NQK * 2);
  short* KB      = (short*)alloc((size_t)MR * NQK * 2);
  short* VB      = (short*)alloc((size_t)MR * NVD * 2);
  short* VT      = (short*)alloc((size_t)MR * NVD * 2);
  short* AO      = (short*)alloc((size_t)MR * NVD * 2);

  hipMemsetAsync(PMAX, 0, 4, stream);
  k_f32_to_bf16<<<2048, 256, 0, stream>>>(x, XB, MR * CC);
  k_transpose_w<<<dim3(NQK / 32, CC / 32), dim3(32, 8), 0, stream>>>(Wq, WQT, CC, NQK);
  k_transpose_w<<<dim3(NQK / 32, CC / 32), dim3(32, 8), 0, stream>>>(Wk, WKT, CC, NQK);
  k_transpose_w<<<dim3(NVD / 32, CC / 32), dim3(32, 8), 0, stream>>>(Wv, WVT, CC, NVD);
  k_transpose_w<<<dim3(CC / 32, NVD / 32), dim3(32, 8), 0, stream>>>(Wo, WOT, NVD, CC);
  k_pdfmax<<<64, 256, 0, stream>>>(PMAX);
  k_build_r<<<2048, 256, 0, stream>>>(WR, PMAX, RB);
  k_gemm<1><<<dim3(MR / 128, NQK / 128), 256, 0, stream>>>(XB, WQT, MR, NQK, CC, bq, uu, QS, QP);
  k_gemm<0><<<dim3(MR / 128, NQK / 128), 256, 0, stream>>>(XB, WKT, MR, NQK, CC, bk, nullptr, KB, nullptr);
  k_gemm<0><<<dim3(MR / 128, NVD / 128), 256, 0, stream>>>(XB, WVT, MR, NVD, CC, bv, nullptr, VB, nullptr);
  k_transpose_v<<<dim3(LL / 32, VDIM / 32, BB * HH), dim3(32, 8), 0, stream>>>(VB, VT);
  k_attn<<<dim3(LL / 128 * BB * HH), 256, 0, stream>>>(QP, QS, KB, VT, RB, AO);
  k_gemm<2><<<dim3(MR / 128, CC / 128), 256, 0, stream>>>(AO, WOT, MR, CC, NVD, bo, nullptr, d_out, nullptr);
}